// Round 2
// baseline (569.208 us; speedup 1.0000x reference)
//
#include <hip/hip_runtime.h>
#include <stdint.h>

// ---------------------------------------------------------------------------
// Types / helpers
// ---------------------------------------------------------------------------
typedef __attribute__((ext_vector_type(8))) short short8;   // 8 bf16 = 16B
typedef __attribute__((ext_vector_type(4))) short short4v;  // 4 bf16 = 8B
typedef __attribute__((ext_vector_type(4))) float f32x4;

#define DEV static __device__ __forceinline__

DEV short f2bf(float f) {
  union { float f; uint32_t u; } v; v.f = f;
  uint32_t r = (v.u + 0x7fffu + ((v.u >> 16) & 1u)) >> 16;  // RNE
  return (short)(uint16_t)r;
}
DEV float bf2f(short s) {
  union { uint32_t u; float f; } v; v.u = ((uint32_t)(uint16_t)s) << 16;
  return v.f;
}
DEV int imin(int a, int b) { return a < b ? a : b; }

// Problem constants
// B=4, S=2048, D=640, H=8, d=80, C=768, A=16

// ---------------------------------------------------------------------------
// 0. dtype detector: bf16 data has bf16-exponent-shaped bits in u16 low half
// ---------------------------------------------------------------------------
__global__ void k_detect(const uint32_t* __restrict__ src, int* __restrict__ flag) {
  __shared__ int cnt;
  if (threadIdx.x == 0) cnt = 0;
  __syncthreads();
  uint32_t u = src[threadIdx.x];
  int e = (int)((u >> 7) & 0xffu);   // exponent field if low 16 bits are a bf16
  if (e >= 110 && e <= 135) atomicAdd(&cnt, 1);
  __syncthreads();
  if (threadIdx.x == 0) *flag = (cnt > 128) ? 1 : 0;  // 1 = inputs are bf16
}

// ---------------------------------------------------------------------------
// 1. converters -> canonical bf16 / f32 workspace buffers
// ---------------------------------------------------------------------------
__global__ void k_conv_vec(const void* __restrict__ src, short* __restrict__ dst,
                           int n4, const int* __restrict__ flag) {
  int i = blockIdx.x * 256 + threadIdx.x;
  if (i >= n4) return;
  if (*flag) {
    ((short4v*)dst)[i] = ((const short4v*)src)[i];
  } else {
    f32x4 v = ((const f32x4*)src)[i];
    short4v o;
    o[0] = f2bf(v[0]); o[1] = f2bf(v[1]); o[2] = f2bf(v[2]); o[3] = f2bf(v[3]);
    ((short4v*)dst)[i] = o;
  }
}

__global__ void k_conv_f32(const void* __restrict__ src, float* __restrict__ dst,
                           int n, const int* __restrict__ flag) {
  int i = blockIdx.x * 256 + threadIdx.x;
  if (i >= n) return;
  dst[i] = (*flag) ? bf2f(((const short*)src)[i]) : ((const float*)src)[i];
}

// transpose+convert: src [K][N] (f32 or bf16) -> dst [N][K] bf16
__global__ void k_conv_t(const void* __restrict__ src, short* __restrict__ dst,
                         int K, int N, const int* __restrict__ flag) {
  __shared__ float tile[32][33];
  int n0 = blockIdx.x * 32, k0 = blockIdx.y * 32;
  int tx = threadIdx.x, ty = threadIdx.y;  // 32 x 8
  int isbf = *flag;
#pragma unroll
  for (int i = 0; i < 4; i++) {
    int r = k0 + ty + i * 8, c = n0 + tx;
    float v = 0.f;
    if (r < K && c < N)
      v = isbf ? bf2f(((const short*)src)[(size_t)r * N + c])
               : ((const float*)src)[(size_t)r * N + c];
    tile[ty + i * 8][tx] = v;
  }
  __syncthreads();
#pragma unroll
  for (int i = 0; i < 4; i++) {
    int n = n0 + ty + i * 8, k = k0 + tx;
    if (n < N && k < K) dst[(size_t)n * K + k] = f2bf(tile[tx][ty + i * 8]);
  }
}

// ---------------------------------------------------------------------------
// 2. MFMA GEMM: C[M,N] = A[M,K] @ Wt[N,K]^T, 128x128 tile, 4 waves, BK=32
//    EPI 0: C=bf16(acc)
//    EPI 1: C=silu(acc+bias)           (bf16)
//    EPI 2: C=x1 + sigmoid(acc+bias)*x2 (bf16)
//    EPI 3: C=acc+bias+res             (FLOAT32 out -> d_out)
// ---------------------------------------------------------------------------
template <int EPI>
__global__ __launch_bounds__(256) void k_gemm_bt(
    const short* __restrict__ A, const short* __restrict__ Wt, void* __restrict__ Cout,
    int M, int N, int K,
    const float* __restrict__ bias, const short* __restrict__ x1,
    const short* __restrict__ x2, const short* __restrict__ res) {
  __shared__ __align__(16) short As[128 * 32];
  __shared__ __align__(16) short Bs[128 * 32];
  const int t = threadIdx.x;
  const int w = t >> 6, ln = t & 63;
  const int wm = w >> 1, wn = w & 1;
  const int m0 = blockIdx.y * 128, n0 = blockIdx.x * 128;
  const int srow = t >> 2, scol = (t & 3) * 8;
  const int lrow = ln & 15, ko = (ln >> 4) * 8;

  f32x4 acc[4][4];
#pragma unroll
  for (int i = 0; i < 4; i++)
#pragma unroll
    for (int j = 0; j < 4; j++) acc[i][j] = (f32x4){0.f, 0.f, 0.f, 0.f};

  for (int k0 = 0; k0 < K; k0 += 32) {
    __syncthreads();
#pragma unroll
    for (int c = 0; c < 2; c++) {
      int r = srow + c * 64;
      int ra = imin(m0 + r, M - 1);
      *(short8*)&As[r * 32 + scol] = *(const short8*)(A + (size_t)ra * K + k0 + scol);
      int rb = imin(n0 + r, N - 1);
      *(short8*)&Bs[r * 32 + scol] = *(const short8*)(Wt + (size_t)rb * K + k0 + scol);
    }
    __syncthreads();
    short8 af[4], bfr[4];
#pragma unroll
    for (int i = 0; i < 4; i++) af[i] = *(const short8*)&As[(wm * 64 + i * 16 + lrow) * 32 + ko];
#pragma unroll
    for (int j = 0; j < 4; j++) bfr[j] = *(const short8*)&Bs[(wn * 64 + j * 16 + lrow) * 32 + ko];
#pragma unroll
    for (int i = 0; i < 4; i++)
#pragma unroll
      for (int j = 0; j < 4; j++)
        acc[i][j] = __builtin_amdgcn_mfma_f32_16x16x32_bf16(af[i], bfr[j], acc[i][j], 0, 0, 0);
  }

  const int rb0 = m0 + wm * 64 + (ln >> 4) * 4;
#pragma unroll
  for (int i = 0; i < 4; i++) {
#pragma unroll
    for (int j = 0; j < 4; j++) {
      int col = n0 + wn * 64 + j * 16 + lrow;
      if (col >= N) continue;
#pragma unroll
      for (int r = 0; r < 4; r++) {
        int row = rb0 + i * 16 + r;
        if (row >= M) continue;
        float v = acc[i][j][r];
        size_t off = (size_t)row * N + col;
        if (EPI == 0) {
          ((short*)Cout)[off] = f2bf(v);
        } else if (EPI == 1) {
          float x = v + bias[col];
          ((short*)Cout)[off] = f2bf(x / (1.f + __expf(-x)));          // SiLU
        } else if (EPI == 2) {
          float g = 1.f / (1.f + __expf(-(v + bias[col])));  // sigmoid gate
          ((short*)Cout)[off] = f2bf(bf2f(x1[off]) + g * bf2f(x2[off]));
        } else {
          // final output: FLOAT32 (reference output dtype)
          ((float*)Cout)[off] = v + bias[col] + bf2f(res[off]);
        }
      }
    }
  }
}

// ---------------------------------------------------------------------------
// 3. V -> V^T  ([bh][d=80][S=2048]) for contiguous PV B-fragments
// ---------------------------------------------------------------------------
__global__ __launch_bounds__(256) void k_build_vt(const short* __restrict__ qkv,
                                                  short* __restrict__ vt) {
  __shared__ __align__(16) short T[128 * 80];
  const int bh = blockIdx.y, st = blockIdx.x;
  const int b = bh >> 3, h = bh & 7;
  const int t = threadIdx.x;
  for (int c = t; c < 1280; c += 256) {
    int r = c / 10, blk = c % 10;
    *(short8*)&T[r * 80 + blk * 8] =
        *(const short8*)(qkv + (size_t)(b * 2048 + st * 128 + r) * 1920 + 1280 + h * 80 + blk * 8);
  }
  __syncthreads();
  for (int c = t; c < 1280; c += 256) {
    int d = c % 80, sc = c / 80;
    short8 v;
#pragma unroll
    for (int i = 0; i < 8; i++) v[i] = T[(sc * 8 + i) * 80 + d];
    *(short8*)(vt + ((size_t)bh * 80 + d) * 2048 + st * 128 + sc * 8) = v;
  }
}

// ---------------------------------------------------------------------------
// 4. Flash attention: block = (q-tile 64 rows, bh); 4 waves x 16 q-rows
// ---------------------------------------------------------------------------
__global__ __launch_bounds__(256) void k_attn(const short* __restrict__ qkv,
                                              const short* __restrict__ vt,
                                              short* __restrict__ outp) {
  __shared__ __align__(16) short Qs[64 * 96];
  __shared__ __align__(16) short Ks[64 * 96];
  __shared__ __align__(16) char Vs[80 * 128];
  __shared__ __align__(16) char Ps[4][2048];

  const int qt = blockIdx.x, bh = blockIdx.y;
  const int b = bh >> 3, h = bh & 7;
  const int t = threadIdx.x, w = t >> 6, ln = t & 63;
  const int lg = ln >> 4, lr = ln & 15;
  const float scale = 0.111803398875f;  // 1/sqrt(80)
  const float LOG2E = 1.4426950408889634f;

  // stage Q tile (pad cols 80..95 with zero)
  for (int c = t; c < 768; c += 256) {
    int r = c / 12, blk = c % 12;
    short8 v = {0, 0, 0, 0, 0, 0, 0, 0};
    if (blk < 10)
      v = *(const short8*)(qkv + (size_t)(b * 2048 + qt * 64 + r) * 1920 + h * 80 + blk * 8);
    *(short8*)&Qs[r * 96 + blk * 8] = v;
  }

  f32x4 oacc[5];
#pragma unroll
  for (int f = 0; f < 5; f++) oacc[f] = (f32x4){0.f, 0.f, 0.f, 0.f};
  float mrow[4] = {-1e30f, -1e30f, -1e30f, -1e30f};
  float lrowv[4] = {0.f, 0.f, 0.f, 0.f};

  for (int kt = 0; kt < 32; kt++) {
    __syncthreads();
    // stage K tile (pad to 96)
    for (int c = t; c < 768; c += 256) {
      int r = c / 12, blk = c % 12;
      short8 v = {0, 0, 0, 0, 0, 0, 0, 0};
      if (blk < 10)
        v = *(const short8*)(qkv + (size_t)(b * 2048 + kt * 64 + r) * 1920 + 640 + h * 80 + blk * 8);
      *(short8*)&Ks[r * 96 + blk * 8] = v;
    }
    // stage V^T tile, XOR-swizzled (row&7)<<4
    for (int c = t; c < 640; c += 256) {
      int r = c >> 3, blk = c & 7;
      short8 v = *(const short8*)(vt + ((size_t)bh * 80 + r) * 2048 + kt * 64 + blk * 8);
      int dst = (r * 128 + blk * 16) ^ ((r & 7) << 4);
      *(short8*)&Vs[dst] = v;
    }
    __syncthreads();

    // scores: S[16 q][64 kv] per wave
    f32x4 sf[4];
#pragma unroll
    for (int j = 0; j < 4; j++) sf[j] = (f32x4){0.f, 0.f, 0.f, 0.f};
#pragma unroll
    for (int ks = 0; ks < 3; ks++) {
      short8 aq = *(const short8*)&Qs[(w * 16 + lr) * 96 + ks * 32 + lg * 8];
#pragma unroll
      for (int j = 0; j < 4; j++) {
        short8 bk = *(const short8*)&Ks[(j * 16 + lr) * 96 + ks * 32 + lg * 8];
        sf[j] = __builtin_amdgcn_mfma_f32_16x16x32_bf16(aq, bk, sf[j], 0, 0, 0);
      }
    }

    // online softmax (rows = lg*4+r, cols spread over 16 lanes x 4 frags)
    float mnew[4], fr[4], psum[4];
#pragma unroll
    for (int r = 0; r < 4; r++) {
      float m = fmaxf(fmaxf(sf[0][r], sf[1][r]), fmaxf(sf[2][r], sf[3][r]));
#pragma unroll
      for (int off = 8; off >= 1; off >>= 1) m = fmaxf(m, __shfl_xor(m, off, 64));
      m *= scale;
      mnew[r] = fmaxf(mrow[r], m);
      fr[r] = exp2f((mrow[r] - mnew[r]) * LOG2E);
      psum[r] = 0.f;
    }
    char* Pw = Ps[w];
#pragma unroll
    for (int j = 0; j < 4; j++) {
#pragma unroll
      for (int r = 0; r < 4; r++) {
        float p = exp2f((sf[j][r] * scale - mnew[r]) * LOG2E);
        psum[r] += p;
        int row = lg * 4 + r, col = j * 16 + lr;
        int addr = (row * 128 + col * 2) ^ ((row & 7) << 4);
        *(short*)&Pw[addr] = f2bf(p);
      }
    }
#pragma unroll
    for (int r = 0; r < 4; r++) {
      float sum = psum[r];
#pragma unroll
      for (int off = 8; off >= 1; off >>= 1) sum += __shfl_xor(sum, off, 64);
      lrowv[r] = lrowv[r] * fr[r] + sum;
      mrow[r] = mnew[r];
    }
#pragma unroll
    for (int f = 0; f < 5; f++) {
      f32x4 a = oacc[f];
#pragma unroll
      for (int r = 0; r < 4; r++) a[r] *= fr[r];
      oacc[f] = a;
    }
    __syncthreads();

    // PV: O += P[16 q][64 kv] @ V[64 kv][80 d]
#pragma unroll
    for (int ks = 0; ks < 2; ks++) {
      short8 ap = *(const short8*)&Pw[(lr * 128 + ks * 64 + lg * 16) ^ ((lr & 7) << 4)];
#pragma unroll
      for (int f = 0; f < 5; f++) {
        int vrow = f * 16 + lr;
        short8 bv = *(const short8*)&Vs[(vrow * 128 + ks * 64 + lg * 16) ^ ((vrow & 7) << 4)];
        oacc[f] = __builtin_amdgcn_mfma_f32_16x16x32_bf16(ap, bv, oacc[f], 0, 0, 0);
      }
    }
  }

  // epilogue: divide by l, store [B,S,H*d]
#pragma unroll
  for (int f = 0; f < 5; f++) {
#pragma unroll
    for (int r = 0; r < 4; r++) {
      int q = qt * 64 + w * 16 + lg * 4 + r;
      float o = oacc[f][r] / lrowv[r];
      outp[(size_t)(b * 2048 + q) * 640 + h * 80 + f * 16 + lr] = f2bf(o);
    }
  }
}

// ---------------------------------------------------------------------------
// 5. AU cross-attention (A=16 kv): thread = (s, h), au_k/au_v staged in LDS
// ---------------------------------------------------------------------------
__global__ __launch_bounds__(256) void k_au_attn(const short* __restrict__ qkv,
                                                 const short* __restrict__ auk,
                                                 const short* __restrict__ auv,
                                                 const float* __restrict__ temp,
                                                 short* __restrict__ auhs) {
  __shared__ __align__(16) short aK[16 * 640];
  __shared__ __align__(16) short aV[16 * 640];
  const int b = blockIdx.y;
  const int t = threadIdx.x;
  for (int c = t; c < 2560; c += 256) {
    int arr = c / 1280, cc = c - arr * 1280;
    int r = cc / 80, blk = cc % 80;
    const short* s = (arr ? auv : auk) + (size_t)(b * 16 + r) * 640 + blk * 8;
    short* d = (arr ? aV : aK) + r * 640 + blk * 8;
    *(short8*)d = *(const short8*)s;
  }
  __syncthreads();
  const int sl = t & 31, h = t >> 5;
  const int s = blockIdx.x * 32 + sl;
  const float alpha = 0.111803398875f * temp[0];
  const float LOG2E = 1.4426950408889634f;

  float qf[80];
  {
    const short* q = qkv + (size_t)(b * 2048 + s) * 1920 + h * 80;
#pragma unroll
    for (int c = 0; c < 10; c++) {
      short8 v = *(const short8*)(q + c * 8);
#pragma unroll
      for (int j = 0; j < 8; j++) qf[c * 8 + j] = bf2f(v[j]);
    }
  }
  float lgt[16];
#pragma unroll
  for (int a = 0; a < 16; a++) {
    const short* kr = &aK[a * 640 + h * 80];
    float acc = 0.f;
#pragma unroll
    for (int c = 0; c < 10; c++) {
      short8 v = *(const short8*)(kr + c * 8);
#pragma unroll
      for (int j = 0; j < 8; j++) acc += qf[c * 8 + j] * bf2f(v[j]);
    }
    lgt[a] = acc * alpha;
  }
  float m = lgt[0];
#pragma unroll
  for (int a = 1; a < 16; a++) m = fmaxf(m, lgt[a]);
  float se = 0.f;
#pragma unroll
  for (int a = 0; a < 16; a++) {
    lgt[a] = exp2f((lgt[a] - m) * LOG2E);
    se += lgt[a];
  }
  float inv = 1.f / se;

  float o[80];
#pragma unroll
  for (int i = 0; i < 80; i++) o[i] = 0.f;
#pragma unroll
  for (int a = 0; a < 16; a++) {
    float pa = lgt[a] * inv;
    const short* vr = &aV[a * 640 + h * 80];
#pragma unroll
    for (int c = 0; c < 10; c++) {
      short8 v = *(const short8*)(vr + c * 8);
#pragma unroll
      for (int j = 0; j < 8; j++) o[c * 8 + j] += pa * bf2f(v[j]);
    }
  }
  short* op = auhs + (size_t)(b * 2048 + s) * 640 + h * 80;
#pragma unroll
  for (int c = 0; c < 10; c++) {
    short8 v;
#pragma unroll
    for (int j = 0; j < 8; j++) v[j] = f2bf(o[c * 8 + j]);
    *(short8*)(op + c * 8) = v;
  }
}

// ---------------------------------------------------------------------------
// Orchestration
// ---------------------------------------------------------------------------
extern "C" void kernel_launch(void* const* d_in, const int* in_sizes, int n_in,
                              void* d_out, int out_size, void* d_ws, size_t ws_size,
                              hipStream_t stream) {
  (void)in_sizes; (void)n_in; (void)out_size; (void)ws_size;

  const void* hidden = d_in[0];
  const void* auemb  = d_in[1];
  const void* wq = d_in[2];
  const void* wk = d_in[3];
  const void* wv = d_in[4];
  const void* wak = d_in[5];
  const void* wav = d_in[6];
  const void* wg1 = d_in[7];
  const void* bg1 = d_in[8];
  const void* wg2 = d_in[9];
  const void* bg2 = d_in[10];
  const void* wout = d_in[11];
  const void* bout = d_in[12];
  const void* tmpr = d_in[13];

  char* ws = (char*)d_ws;
  int* FLAG   = (int*)(ws + 0);
  float* BG1  = (float*)(ws + 1024);
  float* BG2  = (float*)(ws + 4096);
  float* BOUT = (float*)(ws + 8192);
  float* TEMP = (float*)(ws + 12288);

  size_t o = 16384;
  short* HSB = (short*)(ws + o);    o += 10485760;  // hidden bf16 [8192][640]
  short* AUB = (short*)(ws + o);    o += 98304;     // au_emb bf16 [64][768]
  short* WQKVT = (short*)(ws + o);  o += 2457600;   // [1920][640]
  short* WAKT = (short*)(ws + o);   o += 983040;    // [640][768]
  short* WAVT = (short*)(ws + o);   o += 983040;
  short* WG1T = (short*)(ws + o);   o += 409600;    // [320][640]
  short* WG2T = (short*)(ws + o);   o += 409600;    // [640][320]
  short* WOUTT = (short*)(ws + o);  o += 819200;    // [640][640]
  short* QKV = (short*)(ws + o);    o += 31457280;  // [8192][1920]
  short* VT = (short*)(ws + o);     o += 10485760;  // [32][80][2048]
  short* AUK = (short*)(ws + o);    o += 81920;     // [64][640]
  short* AUV = (short*)(ws + o);    o += 81920;
  short* HSATTN = (short*)(ws + o); o += 10485760;  // [8192][640]
  short* AUHS = (short*)(ws + o);   o += 10485760;  // [8192][640]
  // reuse the QKV region after attention for G1/HSMIX
  short* G1 = QKV;                                   // [8192][320]
  short* HSMIX = QKV + 5242880;                      // [8192][640]

  k_detect<<<1, 256, 0, stream>>>((const uint32_t*)hidden, FLAG);

  k_conv_vec<<<5120, 256, 0, stream>>>(hidden, HSB, 1310720, FLAG);
  k_conv_vec<<<48, 256, 0, stream>>>(auemb, AUB, 12288, FLAG);

  dim3 tb(32, 8);
  k_conv_t<<<dim3(20, 20), tb, 0, stream>>>(wq, WQKVT, 640, 640, FLAG);
  k_conv_t<<<dim3(20, 20), tb, 0, stream>>>(wk, WQKVT + 640 * 640, 640, 640, FLAG);
  k_conv_t<<<dim3(20, 20), tb, 0, stream>>>(wv, WQKVT + 2 * 640 * 640, 640, 640, FLAG);
  k_conv_t<<<dim3(20, 24), tb, 0, stream>>>(wak, WAKT, 768, 640, FLAG);
  k_conv_t<<<dim3(20, 24), tb, 0, stream>>>(wav, WAVT, 768, 640, FLAG);
  k_conv_t<<<dim3(10, 20), tb, 0, stream>>>(wg1, WG1T, 640, 320, FLAG);
  k_conv_t<<<dim3(20, 10), tb, 0, stream>>>(wg2, WG2T, 320, 640, FLAG);
  k_conv_t<<<dim3(20, 20), tb, 0, stream>>>(wout, WOUTT, 640, 640, FLAG);
  k_conv_f32<<<2, 256, 0, stream>>>(bg1, BG1, 320, FLAG);
  k_conv_f32<<<3, 256, 0, stream>>>(bg2, BG2, 640, FLAG);
  k_conv_f32<<<3, 256, 0, stream>>>(bout, BOUT, 640, FLAG);
  k_conv_f32<<<1, 256, 0, stream>>>(tmpr, TEMP, 1, FLAG);

  // QKV projection: [8192,640] @ [640,1920]
  k_gemm_bt<0><<<dim3(15, 64), 256, 0, stream>>>(HSB, WQKVT, QKV, 8192, 1920, 640,
                                                 nullptr, nullptr, nullptr, nullptr);
  // au_k / au_v: [64,768] @ [768,640]
  k_gemm_bt<0><<<dim3(5, 1), 256, 0, stream>>>(AUB, WAKT, AUK, 64, 640, 768,
                                               nullptr, nullptr, nullptr, nullptr);
  k_gemm_bt<0><<<dim3(5, 1), 256, 0, stream>>>(AUB, WAVT, AUV, 64, 640, 768,
                                               nullptr, nullptr, nullptr, nullptr);

  k_build_vt<<<dim3(16, 32), 256, 0, stream>>>(QKV, VT);
  k_attn<<<dim3(32, 32), 256, 0, stream>>>(QKV, VT, HSATTN);
  k_au_attn<<<dim3(64, 4), 256, 0, stream>>>(QKV, AUK, AUV, TEMP, AUHS);

  // gate MLP: G1 = silu(au_hs@Wg1+b1); HSMIX = hs_attn + sigmoid(G1@Wg2+b2)*au_hs
  k_gemm_bt<1><<<dim3(3, 64), 256, 0, stream>>>(AUHS, WG1T, G1, 8192, 320, 640,
                                                BG1, nullptr, nullptr, nullptr);
  k_gemm_bt<2><<<dim3(5, 64), 256, 0, stream>>>(G1, WG2T, HSMIX, 8192, 640, 320,
                                                BG2, HSATTN, AUHS, nullptr);
  // out = HSMIX@Wout + b_out + residual  (float32 output)
  k_gemm_bt<3><<<dim3(5, 64), 256, 0, stream>>>(HSMIX, WOUTT, d_out, 8192, 640, 640,
                                                BOUT, nullptr, nullptr, HSB);
}

// Round 3
// 459.082 us; speedup vs baseline: 1.2399x; 1.2399x over previous
//
#include <hip/hip_runtime.h>
#include <stdint.h>

// ---------------------------------------------------------------------------
// Types / helpers
// ---------------------------------------------------------------------------
typedef __attribute__((ext_vector_type(8))) short short8;   // 8 bf16 = 16B
typedef __attribute__((ext_vector_type(4))) short short4v;  // 4 bf16 = 8B
typedef __attribute__((ext_vector_type(4))) float f32x4;

#define DEV static __device__ __forceinline__

DEV short f2bf(float f) {
  union { float f; uint32_t u; } v; v.f = f;
  uint32_t r = (v.u + 0x7fffu + ((v.u >> 16) & 1u)) >> 16;  // RNE
  return (short)(uint16_t)r;
}
DEV float bf2f(short s) {
  union { uint32_t u; float f; } v; v.u = ((uint32_t)(uint16_t)s) << 16;
  return v.f;
}
DEV int imin(int a, int b) { return a < b ? a : b; }

// Problem constants: B=4, S=2048, D=640, H=8, d=80, C=768, A=16

// ---------------------------------------------------------------------------
// 0. dtype detector
// ---------------------------------------------------------------------------
__global__ void k_detect(const uint32_t* __restrict__ src, int* __restrict__ flag) {
  __shared__ int cnt;
  if (threadIdx.x == 0) cnt = 0;
  __syncthreads();
  uint32_t u = src[threadIdx.x];
  int e = (int)((u >> 7) & 0xffu);
  if (e >= 110 && e <= 135) atomicAdd(&cnt, 1);
  __syncthreads();
  if (threadIdx.x == 0) *flag = (cnt > 128) ? 1 : 0;
}

// ---------------------------------------------------------------------------
// 1. converters -> canonical bf16 / f32 workspace buffers
// ---------------------------------------------------------------------------
__global__ void k_conv_vec(const void* __restrict__ src, short* __restrict__ dst,
                           int n4, const int* __restrict__ flag) {
  int i = blockIdx.x * 256 + threadIdx.x;
  if (i >= n4) return;
  if (*flag) {
    ((short4v*)dst)[i] = ((const short4v*)src)[i];
  } else {
    f32x4 v = ((const f32x4*)src)[i];
    short4v o;
    o[0] = f2bf(v[0]); o[1] = f2bf(v[1]); o[2] = f2bf(v[2]); o[3] = f2bf(v[3]);
    ((short4v*)dst)[i] = o;
  }
}

__global__ void k_conv_f32(const void* __restrict__ src, float* __restrict__ dst,
                           int n, const int* __restrict__ flag) {
  int i = blockIdx.x * 256 + threadIdx.x;
  if (i >= n) return;
  dst[i] = (*flag) ? bf2f(((const short*)src)[i]) : ((const float*)src)[i];
}

// transpose+convert: src [K][N] (f32 or bf16) -> dst [N][K] bf16
__global__ void k_conv_t(const void* __restrict__ src, short* __restrict__ dst,
                         int K, int N, const int* __restrict__ flag) {
  __shared__ float tile[32][33];
  int n0 = blockIdx.x * 32, k0 = blockIdx.y * 32;
  int tx = threadIdx.x, ty = threadIdx.y;  // 32 x 8
  int isbf = *flag;
#pragma unroll
  for (int i = 0; i < 4; i++) {
    int r = k0 + ty + i * 8, c = n0 + tx;
    float v = 0.f;
    if (r < K && c < N)
      v = isbf ? bf2f(((const short*)src)[(size_t)r * N + c])
               : ((const float*)src)[(size_t)r * N + c];
    tile[ty + i * 8][tx] = v;
  }
  __syncthreads();
#pragma unroll
  for (int i = 0; i < 4; i++) {
    int n = n0 + ty + i * 8, k = k0 + tx;
    if (n < N && k < K) dst[(size_t)n * K + k] = f2bf(tile[tx][ty + i * 8]);
  }
}

// ---------------------------------------------------------------------------
// 2. MFMA GEMM (m97 staging: global_load_lds width 16, linear LDS)
//    C[M,N] = A[M,K] @ Wt[N,K]^T, 128x128 tile, 4 waves, BK=32
// ---------------------------------------------------------------------------
template <int EPI>
__global__ __launch_bounds__(256) void k_gemm_bt(
    const short* __restrict__ A, const short* __restrict__ Wt, void* __restrict__ Cout,
    int M, int N, int K,
    const float* __restrict__ bias, const short* __restrict__ x1,
    const short* __restrict__ x2, const short* __restrict__ res) {
  __shared__ __align__(16) short As[128 * 32];
  __shared__ __align__(16) short Bs[128 * 32];
  const int t = threadIdx.x;
  const int w = t >> 6, ln = t & 63;
  const int wm = w >> 1, wn = w & 1;
  const int m0 = blockIdx.y * 128, n0 = blockIdx.x * 128;
  const int srow = t >> 2, scol = (t & 3) * 8;
  const int lrow = ln & 15, ko = (ln >> 4) * 8;

  f32x4 acc[4][4];
#pragma unroll
  for (int i = 0; i < 4; i++)
#pragma unroll
    for (int j = 0; j < 4; j++) acc[i][j] = (f32x4){0.f, 0.f, 0.f, 0.f};

  for (int k0 = 0; k0 < K; k0 += 32) {
    __syncthreads();
    // async global -> LDS staging, lane ln lands at wavebase + ln*16 bytes
#pragma unroll
    for (int c = 0; c < 2; c++) {
      int r = srow + c * 64;
      int ra = imin(m0 + r, M - 1);
      int rb = imin(n0 + r, N - 1);
      __builtin_amdgcn_global_load_lds(
          (const __attribute__((address_space(1))) void*)(A + (size_t)ra * K + k0 + scol),
          (__attribute__((address_space(3))) void*)&As[(c * 64 + w * 16) * 32],
          16, 0, 0);
      __builtin_amdgcn_global_load_lds(
          (const __attribute__((address_space(1))) void*)(Wt + (size_t)rb * K + k0 + scol),
          (__attribute__((address_space(3))) void*)&Bs[(c * 64 + w * 16) * 32],
          16, 0, 0);
    }
    __syncthreads();
    short8 af[4], bfr[4];
#pragma unroll
    for (int i = 0; i < 4; i++) af[i] = *(const short8*)&As[(wm * 64 + i * 16 + lrow) * 32 + ko];
#pragma unroll
    for (int j = 0; j < 4; j++) bfr[j] = *(const short8*)&Bs[(wn * 64 + j * 16 + lrow) * 32 + ko];
#pragma unroll
    for (int i = 0; i < 4; i++)
#pragma unroll
      for (int j = 0; j < 4; j++)
        acc[i][j] = __builtin_amdgcn_mfma_f32_16x16x32_bf16(af[i], bfr[j], acc[i][j], 0, 0, 0);
  }

  const int rb0 = m0 + wm * 64 + (ln >> 4) * 4;
#pragma unroll
  for (int i = 0; i < 4; i++) {
#pragma unroll
    for (int j = 0; j < 4; j++) {
      int col = n0 + wn * 64 + j * 16 + lrow;
      if (col >= N) continue;
#pragma unroll
      for (int r = 0; r < 4; r++) {
        int row = rb0 + i * 16 + r;
        if (row >= M) continue;
        float v = acc[i][j][r];
        size_t off = (size_t)row * N + col;
        if (EPI == 0) {
          ((short*)Cout)[off] = f2bf(v);
        } else if (EPI == 1) {
          float x = v + bias[col];
          ((short*)Cout)[off] = f2bf(x / (1.f + __expf(-x)));          // SiLU
        } else if (EPI == 2) {
          float g = 1.f / (1.f + __expf(-(v + bias[col])));            // sigmoid gate
          ((short*)Cout)[off] = f2bf(bf2f(x1[off]) + g * bf2f(x2[off]));
        } else {
          ((float*)Cout)[off] = v + bias[col] + bf2f(res[off]);        // f32 final out
        }
      }
    }
  }
}

// ---------------------------------------------------------------------------
// 3. V -> V^T with per-64 kv-permutation pi(c) = (c&15)*4 + (c>>4)
//    vt[bh][dd][tile*64 + p] = V[tile*64 + inv_pi(p)][dd], inv_pi(p)=(p>>2)+16*(p&3)
// ---------------------------------------------------------------------------
__global__ __launch_bounds__(256) void k_build_vt(const short* __restrict__ qkv,
                                                  short* __restrict__ vt) {
  __shared__ __align__(16) short T[128 * 80];
  const int bh = blockIdx.y, st = blockIdx.x;
  const int b = bh >> 3, h = bh & 7;
  const int t = threadIdx.x;
  for (int c = t; c < 1280; c += 256) {
    int r = c / 10, blk = c % 10;
    *(short8*)&T[r * 80 + blk * 8] =
        *(const short8*)(qkv + (size_t)(b * 2048 + st * 128 + r) * 1920 + 1280 + h * 80 + blk * 8);
  }
  __syncthreads();
  for (int c = t; c < 1280; c += 256) {
    int dd = c % 80, qc = (c / 80) * 8;  // output position chunk within 128 rows
    short8 v;
#pragma unroll
    for (int i = 0; i < 8; i++) {
      int q = qc + i;
      int tile = q >> 6, p = q & 63;
      int src = (tile << 6) + (p >> 2) + ((p & 3) << 4);  // inv_pi
      v[i] = T[src * 80 + dd];
    }
    *(short8*)(vt + ((size_t)bh * 80 + dd) * 2048 + st * 128 + qc) = v;
  }
}

// ---------------------------------------------------------------------------
// 4. Flash attention: block = (64 q-rows, bh); 4 waves x 16 q-rows, KVBLK=64
//    Q in regs; Ks stride 104 (conflict-free); P b64 writes via pi; T14 prefetch
// ---------------------------------------------------------------------------
__global__ __launch_bounds__(256) void k_attn(const short* __restrict__ qkv,
                                              const short* __restrict__ vt,
                                              short* __restrict__ outp) {
  __shared__ __align__(16) short Ks[64 * 104];
  __shared__ __align__(16) char Vs[80 * 128];
  __shared__ __align__(16) char Ps[4][2048];

  const int qt = blockIdx.x, bh = blockIdx.y;
  const int b = bh >> 3, h = bh & 7;
  const int t = threadIdx.x, w = t >> 6, ln = t & 63;
  const int lg = ln >> 4, lr = ln & 15;
  const float scale = 0.111803398875f;  // 1/sqrt(80)
  const float LOG2E = 1.4426950408889634f;

  // Q fragments in registers (cols >= 80 are zero)
  short8 qfrag[3];
  {
    const short* qrow = qkv + (size_t)(b * 2048 + qt * 64 + w * 16 + lr) * 1920 + h * 80;
#pragma unroll
    for (int ks = 0; ks < 3; ks++) {
      int off = ks * 32 + lg * 8;
      short8 v = {0, 0, 0, 0, 0, 0, 0, 0};
      if (off < 80) v = *(const short8*)(qrow + off);
      qfrag[ks] = v;
    }
  }

  const short* kbase = qkv + (size_t)b * 2048 * 1920 + 640 + h * 80;
  const short* vbase = vt + (size_t)bh * 80 * 2048;

  int kr[3], kb[3], vr[3], vb[3];
#pragma unroll
  for (int i = 0; i < 3; i++) {
    int c = t + i * 256;
    kr[i] = c / 12; kb[i] = c % 12;   // 768 K-chunks: row 0..63, blk 0..11 (pad >=10)
    vr[i] = c >> 3; vb[i] = c & 7;    // 640 V-chunks: row(d) 0..79, blk 0..7
  }

  short8 kreg[3], vreg[3];
#pragma unroll
  for (int i = 0; i < 3; i++) { kreg[i] = (short8){0,0,0,0,0,0,0,0}; vreg[i] = kreg[i]; }

  // prefetch tile 0
#pragma unroll
  for (int i = 0; i < 3; i++) {
    if (kb[i] < 10) kreg[i] = *(const short8*)(kbase + (size_t)kr[i] * 1920 + kb[i] * 8);
    if (i < 2 || t < 128) vreg[i] = *(const short8*)(vbase + (size_t)vr[i] * 2048 + vb[i] * 8);
  }

  f32x4 oacc[5];
#pragma unroll
  for (int f = 0; f < 5; f++) oacc[f] = (f32x4){0.f, 0.f, 0.f, 0.f};
  float mrow[4] = {-1e30f, -1e30f, -1e30f, -1e30f};
  float lrowv[4] = {0.f, 0.f, 0.f, 0.f};

  for (int kt = 0; kt < 32; kt++) {
    __syncthreads();  // previous tile's compute done
    // write staged regs -> LDS
#pragma unroll
    for (int i = 0; i < 3; i++)
      *(short8*)&Ks[kr[i] * 104 + kb[i] * 8] = kreg[i];
#pragma unroll
    for (int i = 0; i < 3; i++) {
      if (i < 2 || t < 128) {
        int dst = (vr[i] * 128 + vb[i] * 16) ^ ((vr[i] & 7) << 4);
        *(short8*)&Vs[dst] = vreg[i];
      }
    }
    __syncthreads();

    // T14: issue next tile's global loads; consumed at next iteration's writes
    if (kt < 31) {
      const short* kb2 = kbase + (size_t)(kt + 1) * 64 * 1920;
      const short* vb2 = vbase + (size_t)(kt + 1) * 64;
#pragma unroll
      for (int i = 0; i < 3; i++) {
        if (kb[i] < 10) kreg[i] = *(const short8*)(kb2 + (size_t)kr[i] * 1920 + kb[i] * 8);
        if (i < 2 || t < 128) vreg[i] = *(const short8*)(vb2 + (size_t)vr[i] * 2048 + vb[i] * 8);
      }
    }

    // QK^T: S[16 q][64 kv] per wave
    f32x4 sf[4];
#pragma unroll
    for (int j = 0; j < 4; j++) sf[j] = (f32x4){0.f, 0.f, 0.f, 0.f};
#pragma unroll
    for (int ks = 0; ks < 3; ks++) {
#pragma unroll
      for (int j = 0; j < 4; j++) {
        short8 bk = *(const short8*)&Ks[(j * 16 + lr) * 104 + ks * 32 + lg * 8];
        sf[j] = __builtin_amdgcn_mfma_f32_16x16x32_bf16(qfrag[ks], bk, sf[j], 0, 0, 0);
      }
    }

    // online softmax; P stored at physical col pi(c) = lr*4 + j (b64 writes)
    float mnew[4], fr[4], psum[4];
#pragma unroll
    for (int r = 0; r < 4; r++) {
      float m = fmaxf(fmaxf(sf[0][r], sf[1][r]), fmaxf(sf[2][r], sf[3][r]));
#pragma unroll
      for (int off = 8; off >= 1; off >>= 1) m = fmaxf(m, __shfl_xor(m, off, 64));
      m *= scale;
      mnew[r] = fmaxf(mrow[r], m);
      fr[r] = exp2f((mrow[r] - mnew[r]) * LOG2E);
      psum[r] = 0.f;
    }
    char* Pw = Ps[w];
    const float sc2 = scale * LOG2E;
#pragma unroll
    for (int r = 0; r < 4; r++) {
      int row = lg * 4 + r;
      float mn2 = mnew[r] * LOG2E;
      short4v pk;
#pragma unroll
      for (int j = 0; j < 4; j++) {
        float p = exp2f(sf[j][r] * sc2 - mn2);
        psum[r] += p;
        pk[j] = f2bf(p);
      }
      int addr = (row * 128 + lr * 8) ^ ((row & 7) << 4);
      *(short4v*)&Pw[addr] = pk;
    }
#pragma unroll
    for (int r = 0; r < 4; r++) {
      float sum = psum[r];
#pragma unroll
      for (int off = 8; off >= 1; off >>= 1) sum += __shfl_xor(sum, off, 64);
      lrowv[r] = lrowv[r] * fr[r] + sum;
      mrow[r] = mnew[r];
    }
#pragma unroll
    for (int f = 0; f < 5; f++) {
      f32x4 a = oacc[f];
#pragma unroll
      for (int r = 0; r < 4; r++) a[r] *= fr[r];
      oacc[f] = a;
    }

    // PV: O += P[16 q][64 kv_phys] @ V[64 kv_phys][80 d]
#pragma unroll
    for (int ks = 0; ks < 2; ks++) {
      short8 ap = *(const short8*)&Pw[(lr * 128 + ks * 64 + lg * 16) ^ ((lr & 7) << 4)];
#pragma unroll
      for (int f = 0; f < 5; f++) {
        int vrow = f * 16 + lr;
        short8 bv = *(const short8*)&Vs[(vrow * 128 + ks * 64 + lg * 16) ^ ((vrow & 7) << 4)];
        oacc[f] = __builtin_amdgcn_mfma_f32_16x16x32_bf16(ap, bv, oacc[f], 0, 0, 0);
      }
    }
  }

  // epilogue: divide by l, store [B,S,H*d]
#pragma unroll
  for (int f = 0; f < 5; f++) {
#pragma unroll
    for (int r = 0; r < 4; r++) {
      int q = qt * 64 + w * 16 + lg * 4 + r;
      float o = oacc[f][r] / lrowv[r];
      outp[(size_t)(b * 2048 + q) * 640 + h * 80 + f * 16 + lr] = f2bf(o);
    }
  }
}

// ---------------------------------------------------------------------------
// 5. AU cross-attention (A=16 kv)
// ---------------------------------------------------------------------------
__global__ __launch_bounds__(256) void k_au_attn(const short* __restrict__ qkv,
                                                 const short* __restrict__ auk,
                                                 const short* __restrict__ auv,
                                                 const float* __restrict__ temp,
                                                 short* __restrict__ auhs) {
  __shared__ __align__(16) short aK[16 * 640];
  __shared__ __align__(16) short aV[16 * 640];
  const int b = blockIdx.y;
  const int t = threadIdx.x;
  for (int c = t; c < 2560; c += 256) {
    int arr = c / 1280, cc = c - arr * 1280;
    int r = cc / 80, blk = cc % 80;
    const short* s = (arr ? auv : auk) + (size_t)(b * 16 + r) * 640 + blk * 8;
    short* d = (arr ? aV : aK) + r * 640 + blk * 8;
    *(short8*)d = *(const short8*)s;
  }
  __syncthreads();
  const int sl = t & 31, h = t >> 5;
  const int s = blockIdx.x * 32 + sl;
  const float alpha = 0.111803398875f * temp[0];
  const float LOG2E = 1.4426950408889634f;

  float qf[80];
  {
    const short* q = qkv + (size_t)(b * 2048 + s) * 1920 + h * 80;
#pragma unroll
    for (int c = 0; c < 10; c++) {
      short8 v = *(const short8*)(q + c * 8);
#pragma unroll
      for (int j = 0; j < 8; j++) qf[c * 8 + j] = bf2f(v[j]);
    }
  }
  float lgt[16];
#pragma unroll
  for (int a = 0; a < 16; a++) {
    const short* kr = &aK[a * 640 + h * 80];
    float acc = 0.f;
#pragma unroll
    for (int c = 0; c < 10; c++) {
      short8 v = *(const short8*)(kr + c * 8);
#pragma unroll
      for (int j = 0; j < 8; j++) acc += qf[c * 8 + j] * bf2f(v[j]);
    }
    lgt[a] = acc * alpha;
  }
  float m = lgt[0];
#pragma unroll
  for (int a = 1; a < 16; a++) m = fmaxf(m, lgt[a]);
  float se = 0.f;
#pragma unroll
  for (int a = 0; a < 16; a++) {
    lgt[a] = exp2f((lgt[a] - m) * LOG2E);
    se += lgt[a];
  }
  float inv = 1.f / se;

  float o[80];
#pragma unroll
  for (int i = 0; i < 80; i++) o[i] = 0.f;
#pragma unroll
  for (int a = 0; a < 16; a++) {
    float pa = lgt[a] * inv;
    const short* vr = &aV[a * 640 + h * 80];
#pragma unroll
    for (int c = 0; c < 10; c++) {
      short8 v = *(const short8*)(vr + c * 8);
#pragma unroll
      for (int j = 0; j < 8; j++) o[c * 8 + j] += pa * bf2f(v[j]);
    }
  }
  short* op = auhs + (size_t)(b * 2048 + s) * 640 + h * 80;
#pragma unroll
  for (int c = 0; c < 10; c++) {
    short8 v;
#pragma unroll
    for (int j = 0; j < 8; j++) v[j] = f2bf(o[c * 8 + j]);
    *(short8*)(op + c * 8) = v;
  }
}

// ---------------------------------------------------------------------------
// Orchestration
// ---------------------------------------------------------------------------
extern "C" void kernel_launch(void* const* d_in, const int* in_sizes, int n_in,
                              void* d_out, int out_size, void* d_ws, size_t ws_size,
                              hipStream_t stream) {
  (void)in_sizes; (void)n_in; (void)out_size; (void)ws_size;

  const void* hidden = d_in[0];
  const void* auemb  = d_in[1];
  const void* wq = d_in[2];
  const void* wk = d_in[3];
  const void* wv = d_in[4];
  const void* wak = d_in[5];
  const void* wav = d_in[6];
  const void* wg1 = d_in[7];
  const void* bg1 = d_in[8];
  const void* wg2 = d_in[9];
  const void* bg2 = d_in[10];
  const void* wout = d_in[11];
  const void* bout = d_in[12];
  const void* tmpr = d_in[13];

  char* ws = (char*)d_ws;
  int* FLAG   = (int*)(ws + 0);
  float* BG1  = (float*)(ws + 1024);
  float* BG2  = (float*)(ws + 4096);
  float* BOUT = (float*)(ws + 8192);
  float* TEMP = (float*)(ws + 12288);

  size_t o = 16384;
  short* HSB = (short*)(ws + o);    o += 10485760;  // hidden bf16 [8192][640]
  short* AUB = (short*)(ws + o);    o += 98304;     // au_emb bf16 [64][768]
  short* WQKVT = (short*)(ws + o);  o += 2457600;   // [1920][640]
  short* WAKT = (short*)(ws + o);   o += 983040;    // [640][768]
  short* WAVT = (short*)(ws + o);   o += 983040;
  short* WG1T = (short*)(ws + o);   o += 409600;    // [320][640]
  short* WG2T = (short*)(ws + o);   o += 409600;    // [640][320]
  short* WOUTT = (short*)(ws + o);  o += 819200;    // [640][640]
  short* QKV = (short*)(ws + o);    o += 31457280;  // [8192][1920]
  short* VT = (short*)(ws + o);     o += 10485760;  // [32][80][2048] (pi-permuted per 64)
  short* AUK = (short*)(ws + o);    o += 81920;     // [64][640]
  short* AUV = (short*)(ws + o);    o += 81920;
  short* HSATTN = (short*)(ws + o); o += 10485760;  // [8192][640]
  short* AUHS = (short*)(ws + o);   o += 10485760;  // [8192][640]
  short* G1 = QKV;                                   // reuse: [8192][320]
  short* HSMIX = QKV + 5242880;                      // reuse: [8192][640]

  k_detect<<<1, 256, 0, stream>>>((const uint32_t*)hidden, FLAG);

  k_conv_vec<<<5120, 256, 0, stream>>>(hidden, HSB, 1310720, FLAG);
  k_conv_vec<<<48, 256, 0, stream>>>(auemb, AUB, 12288, FLAG);

  dim3 tb(32, 8);
  k_conv_t<<<dim3(20, 20), tb, 0, stream>>>(wq, WQKVT, 640, 640, FLAG);
  k_conv_t<<<dim3(20, 20), tb, 0, stream>>>(wk, WQKVT + 640 * 640, 640, 640, FLAG);
  k_conv_t<<<dim3(20, 20), tb, 0, stream>>>(wv, WQKVT + 2 * 640 * 640, 640, 640, FLAG);
  k_conv_t<<<dim3(20, 24), tb, 0, stream>>>(wak, WAKT, 768, 640, FLAG);
  k_conv_t<<<dim3(20, 24), tb, 0, stream>>>(wav, WAVT, 768, 640, FLAG);
  k_conv_t<<<dim3(10, 20), tb, 0, stream>>>(wg1, WG1T, 640, 320, FLAG);
  k_conv_t<<<dim3(20, 10), tb, 0, stream>>>(wg2, WG2T, 320, 640, FLAG);
  k_conv_t<<<dim3(20, 20), tb, 0, stream>>>(wout, WOUTT, 640, 640, FLAG);
  k_conv_f32<<<2, 256, 0, stream>>>(bg1, BG1, 320, FLAG);
  k_conv_f32<<<3, 256, 0, stream>>>(bg2, BG2, 640, FLAG);
  k_conv_f32<<<3, 256, 0, stream>>>(bout, BOUT, 640, FLAG);
  k_conv_f32<<<1, 256, 0, stream>>>(tmpr, TEMP, 1, FLAG);

  // QKV projection: [8192,640] @ [640,1920]
  k_gemm_bt<0><<<dim3(15, 64), 256, 0, stream>>>(HSB, WQKVT, QKV, 8192, 1920, 640,
                                                 nullptr, nullptr, nullptr, nullptr);
  // au_k / au_v: [64,768] @ [768,640]
  k_gemm_bt<0><<<dim3(5, 1), 256, 0, stream>>>(AUB, WAKT, AUK, 64, 640, 768,
                                               nullptr, nullptr, nullptr, nullptr);
  k_gemm_bt<0><<<dim3(5, 1), 256, 0, stream>>>(AUB, WAVT, AUV, 64, 640, 768,
                                               nullptr, nullptr, nullptr, nullptr);

  k_build_vt<<<dim3(16, 32), 256, 0, stream>>>(QKV, VT);
  k_attn<<<dim3(32, 32), 256, 0, stream>>>(QKV, VT, HSATTN);
  k_au_attn<<<dim3(64, 4), 256, 0, stream>>>(QKV, AUK, AUV, TEMP, AUHS);

  // gate MLP
  k_gemm_bt<1><<<dim3(3, 64), 256, 0, stream>>>(AUHS, WG1T, G1, 8192, 320, 640,
                                                BG1, nullptr, nullptr, nullptr);
  k_gemm_bt<2><<<dim3(5, 64), 256, 0, stream>>>(G1, WG2T, HSMIX, 8192, 640, 320,
                                                BG2, HSATTN, AUHS, nullptr);
  // out = HSMIX@Wout + b_out + residual  (float32 output)
  k_gemm_bt<3><<<dim3(5, 64), 256, 0, stream>>>(HSMIX, WOUTT, d_out, 8192, 640, 640,
                                                BOUT, nullptr, nullptr, HSB);
}